// Round 1
// baseline (728.042 us; speedup 1.0000x reference)
//
#include <hip/hip_runtime.h>

#define N_NODES 20000
#define N_EDGES 320000

typedef __attribute__((ext_vector_type(4))) float f32x4;
typedef __attribute__((ext_vector_type(8))) short s16x8;

__device__ __forceinline__ unsigned short f2b(float f){
  union { float f; unsigned int u; } v; v.f = f;
  unsigned int u = v.u;
  return (unsigned short)((u + 0x7fffu + ((u>>16)&1u)) >> 16);
}
__device__ __forceinline__ float b2f(unsigned short h){
  union { unsigned int u; float f; } v; v.u = ((unsigned int)h)<<16; return v.f;
}
__device__ __forceinline__ float sigm(float x){ return 1.0f/(1.0f+__expf(-x)); }
__device__ __forceinline__ float tanhfast(float x){ return 1.0f - 2.0f/(1.0f+__expf(2.0f*x)); }

// ---------------- weight prep: f32 -> bf16, build Wcat = [We | Whu | Whw] (128 x 384)
__global__ void k_prep(const float* We, const float* Whu, const float* Whw,
                       const float* Wa, const float* Wi, const float* Wh,
                       unsigned short* WcatB, unsigned short* WaB,
                       unsigned short* WiB, unsigned short* WhB){
  int i = blockIdx.x*256 + threadIdx.x;
  if (i < 49152){
    int d = i/384, k = i - d*384;
    float v = (k<128) ? We[d*128+k] : (k<256 ? Whu[d*128+k-128] : Whw[d*128+k-256]);
    WcatB[i] = f2b(v);
  } else if (i < 49152+65536){
    int j = i-49152; WaB[j] = f2b(Wa[j]);
  } else if (i < 49152+65536+49152){
    int j = i-114688; WiB[j] = f2b(Wi[j]);
  } else if (i < 212992){
    int j = i-163840; WhB[j] = f2b(Wh[j]);
  }
}

// ---------------- counting sort by src
__global__ void k_hist(const int* ei, int* cnt){
  int e = blockIdx.x*256 + threadIdx.x;
  atomicAdd(&cnt[ei[e]], 1);
}

__global__ void k_scan(const int* cnt, int* off, int* cursor){
  __shared__ int buf[1024];
  __shared__ int sbase;
  int tid = threadIdx.x;
  if (tid==0) sbase = 0;
  __syncthreads();
  for (int ch=0; ch<20; ++ch){
    int idx = ch*1024 + tid;
    int v = (idx < N_NODES) ? cnt[idx] : 0;
    buf[tid] = v;
    __syncthreads();
    for (int s=1; s<1024; s<<=1){
      int t = (tid >= s) ? buf[tid-s] : 0;
      __syncthreads();
      buf[tid] += t;
      __syncthreads();
    }
    int total = buf[1023];
    int o = sbase + buf[tid] - v;
    if (idx < N_NODES){ off[idx] = o; cursor[idx] = o; }
    __syncthreads();
    if (tid==0) sbase += total;
    __syncthreads();
  }
  if (tid==0) off[N_NODES] = sbase;
}

__global__ void k_scatter(const int* ei, int* cursor, int* sorted){
  int e = blockIdx.x*256 + threadIdx.x;
  int s = ei[e];
  int slot = atomicAdd(&cursor[s], 1);
  sorted[slot] = e;
}

// ---------------- K1: messages = leaky(cat(ea, x[src], x[tgt]) @ Wcat^T)
// 64 edges x 128 out per block, K=384, 4 waves (16 edges each)
__global__ __launch_bounds__(256,2) void k_messages(const float* ea, const int* ei, const float* x,
                                                    const unsigned short* WcatB,
                                                    float* msg_out, unsigned short* msgb){
  const int tid = threadIdx.x;
  const int e0 = blockIdx.x*64;
  __shared__ unsigned short A[64][392];   // 64 x 384 bf16, +8 pad
  __shared__ unsigned short B[128][40];   // 128 x 32 bf16 chunk, +8 pad
  {
    int i = tid>>2, q = tid&3;
    int e = e0 + i;
    int s = ei[e]; int t = ei[N_EDGES + e];
    const float* pe = ea + (size_t)e*128 + q*32;
    const float* ps = x  + (size_t)s*128 + q*32;
    const float* pt = x  + (size_t)t*128 + q*32;
    #pragma unroll
    for (int j=0;j<32;j+=4){
      float4 v = *(const float4*)(pe+j);
      unsigned short w0=f2b(v.x),w1=f2b(v.y),w2=f2b(v.z),w3=f2b(v.w);
      A[i][q*32+j]=w0; A[i][q*32+j+1]=w1; A[i][q*32+j+2]=w2; A[i][q*32+j+3]=w3;
      v = *(const float4*)(ps+j);
      A[i][128+q*32+j]=f2b(v.x); A[i][128+q*32+j+1]=f2b(v.y); A[i][128+q*32+j+2]=f2b(v.z); A[i][128+q*32+j+3]=f2b(v.w);
      v = *(const float4*)(pt+j);
      A[i][256+q*32+j]=f2b(v.x); A[i][256+q*32+j+1]=f2b(v.y); A[i][256+q*32+j+2]=f2b(v.z); A[i][256+q*32+j+3]=f2b(v.w);
    }
  }
  f32x4 acc[8];
  #pragma unroll
  for (int i=0;i<8;++i) acc[i] = (f32x4){0.f,0.f,0.f,0.f};
  const int w = tid>>6, l = tid&63, lr = l&15, lg = l>>4;
  for (int ks=0; ks<12; ++ks){
    __syncthreads();
    {
      int n = tid>>1, c = tid&1;
      const s16x8* src = (const s16x8*)(WcatB + n*384 + ks*32 + c*16);
      *(s16x8*)&B[n][c*16]   = src[0];
      *(s16x8*)&B[n][c*16+8] = src[1];
    }
    __syncthreads();
    s16x8 af = *(const s16x8*)&A[w*16 + lr][ks*32 + lg*8];
    #pragma unroll
    for (int nt=0; nt<8; ++nt){
      s16x8 bf = *(const s16x8*)&B[nt*16 + lr][lg*8];
      acc[nt] = __builtin_amdgcn_mfma_f32_16x16x32_bf16(af, bf, acc[nt], 0,0,0);
    }
  }
  #pragma unroll
  for (int nt=0;nt<8;++nt){
    #pragma unroll
    for (int j=0;j<4;++j){
      int row = e0 + w*16 + lg*4 + j;
      int col = nt*16 + lr;
      float v = acc[nt][j];
      v = (v>0.f) ? v : 0.01f*v;
      msg_out[(size_t)row*128 + col] = v;
      msgb[(size_t)row*128 + col] = f2b(v);
    }
  }
}

// ---------------- K2: per-src-node segment softmax + head-collapse + scatter to agg
// one block (4 waves) per src node; wave w = head w
__global__ __launch_bounds__(256,2) void k_attn(const unsigned short* msgb, const unsigned short* WaB,
                                                const int* ei, const int* off, const int* sorted,
                                                float* agg){
  const int n = blockIdx.x;
  const int o0 = off[n];
  int deg = off[n+1] - o0;
  if (deg <= 0) return;
  int degc = deg < 48 ? deg : 48;
  const int R = (degc + 15) >> 4;
  __shared__ unsigned short A[48][136];    // msg bf16 rows
  __shared__ unsigned short Wl[48][520];   // w = exp(logit) bf16 [row][h*128+d]
  __shared__ float invS[512];
  __shared__ int tgt_l[48];
  const int tid = threadIdx.x;
  #pragma unroll
  for (int p=0;p<3;++p){
    int i = p*16 + (tid>>4); int c = tid&15;
    if (i < degc){
      int e = sorted[o0 + i];
      *(s16x8*)&A[i][c*8] = *(const s16x8*)(msgb + (size_t)e*128 + c*8);
      if (c==0) tgt_l[i] = ei[N_EDGES + e];
    }
  }
  const int w = tid>>6, l = tid&63, lr = l&15, lg = l>>4;
  // preload this head's W_attn slice as B-fragments (32 x 16B = 128 VGPR)
  s16x8 bw[8][4];
  #pragma unroll
  for (int nt=0;nt<8;++nt)
    #pragma unroll
    for (int ks=0;ks<4;++ks)
      bw[nt][ks] = *(const s16x8*)(WaB + ((w*128 + nt*16 + lr)*128 + ks*32 + lg*8));
  __syncthreads();
  float sch[8];
  #pragma unroll
  for (int nt=0;nt<8;++nt) sch[nt]=0.f;
  for (int r=0;r<R;++r){
    f32x4 acc[8];
    #pragma unroll
    for (int i=0;i<8;++i) acc[i] = (f32x4){0.f,0.f,0.f,0.f};
    #pragma unroll
    for (int ks=0;ks<4;++ks){
      s16x8 af = *(const s16x8*)&A[r*16 + lr][ks*32 + lg*8];
      #pragma unroll
      for (int nt=0;nt<8;++nt)
        acc[nt] = __builtin_amdgcn_mfma_f32_16x16x32_bf16(af, bw[nt][ks], acc[nt], 0,0,0);
    }
    #pragma unroll
    for (int nt=0;nt<8;++nt){
      #pragma unroll
      for (int j=0;j<4;++j){
        int row = r*16 + lg*4 + j;
        float wv = 0.f;
        if (row < degc){
          wv = __expf(acc[nt][j]);
          Wl[row][w*128 + nt*16 + lr] = f2b(wv);
        }
        sch[nt] += wv;
      }
    }
  }
  #pragma unroll
  for (int nt=0;nt<8;++nt){
    float s = sch[nt];
    s += __shfl_xor(s, 16, 64);
    s += __shfl_xor(s, 32, 64);
    if (l < 16) invS[w*128 + nt*16 + l] = 1.0f/s;
  }
  __syncthreads();
  for (int idx = tid; idx < degc*128; idx += 256){
    int row = idx>>7, d = idx&127;
    float m = b2f(A[row][d]);
    float sum = 0.f;
    #pragma unroll
    for (int h=0;h<4;++h)
      sum += b2f(Wl[row][h*128+d]) * invS[h*128+d];
    atomicAdd(&agg[(size_t)tgt_l[row]*128 + d], 0.25f * sum * m);
  }
}

// ---------------- K3: GRU cell, 64 nodes per block
__global__ __launch_bounds__(256,2) void k_gru(const float* x, const float* agg,
                                               const unsigned short* WiB, const unsigned short* WhB,
                                               const float* bih, const float* bhh, float* emb){
  const int base = blockIdx.x*64;
  __shared__ unsigned short Ax[64][136];
  __shared__ unsigned short Ag[64][136];
  const int tid = threadIdx.x;
  {
    int i = tid>>2, q = tid&3;
    int node = base + i;
    #pragma unroll
    for (int j=0;j<32;j+=4){
      float4 vx = {0,0,0,0}, vg = {0,0,0,0};
      if (node < N_NODES){
        vx = *(const float4*)(x   + (size_t)node*128 + q*32 + j);
        vg = *(const float4*)(agg + (size_t)node*128 + q*32 + j);
      }
      Ax[i][q*32+j]=f2b(vx.x); Ax[i][q*32+j+1]=f2b(vx.y); Ax[i][q*32+j+2]=f2b(vx.z); Ax[i][q*32+j+3]=f2b(vx.w);
      Ag[i][q*32+j]=f2b(vg.x); Ag[i][q*32+j+1]=f2b(vg.y); Ag[i][q*32+j+2]=f2b(vg.z); Ag[i][q*32+j+3]=f2b(vg.w);
    }
  }
  __syncthreads();
  const int w = tid>>6, l = tid&63, lr = l&15, lg = l>>4;
  float rr[8][4], zz[8][4];
  #pragma unroll
  for (int c=0;c<3;++c){
    f32x4 aI[8], aH[8];
    #pragma unroll
    for (int i=0;i<8;++i){ aI[i]=(f32x4){0.f,0.f,0.f,0.f}; aH[i]=(f32x4){0.f,0.f,0.f,0.f}; }
    #pragma unroll
    for (int ks=0;ks<4;++ks){
      s16x8 ax = *(const s16x8*)&Ax[w*16+lr][ks*32+lg*8];
      s16x8 ag = *(const s16x8*)&Ag[w*16+lr][ks*32+lg*8];
      #pragma unroll
      for (int nt=0;nt<8;++nt){
        s16x8 bI = *(const s16x8*)(WiB + ((c*128 + nt*16 + lr)*128 + ks*32 + lg*8));
        s16x8 bH = *(const s16x8*)(WhB + ((c*128 + nt*16 + lr)*128 + ks*32 + lg*8));
        aI[nt] = __builtin_amdgcn_mfma_f32_16x16x32_bf16(ax, bI, aI[nt], 0,0,0);
        aH[nt] = __builtin_amdgcn_mfma_f32_16x16x32_bf16(ag, bH, aH[nt], 0,0,0);
      }
    }
    #pragma unroll
    for (int nt=0;nt<8;++nt){
      float bI = bih[c*128 + nt*16 + lr];
      float bH = bhh[c*128 + nt*16 + lr];
      #pragma unroll
      for (int j=0;j<4;++j){
        float gi = aI[nt][j] + bI;
        float gh = aH[nt][j] + bH;
        if (c==0){
          rr[nt][j] = sigm(gi + gh);
        } else if (c==1){
          zz[nt][j] = sigm(gi + gh);
        } else {
          float nn = tanhfast(gi + rr[nt][j]*gh);
          int node = base + w*16 + lg*4 + j;
          int d = nt*16 + lr;
          if (node < N_NODES){
            float a = agg[(size_t)node*128 + d];
            float z = zz[nt][j];
            emb[(size_t)node*128 + d] = (1.0f - z)*nn + z*a;
          }
        }
      }
    }
  }
}

extern "C" void kernel_launch(void* const* d_in, const int* in_sizes, int n_in,
                              void* d_out, int out_size, void* d_ws, size_t ws_size,
                              hipStream_t stream){
  (void)in_sizes; (void)n_in; (void)out_size;
  const float* x    = (const float*)d_in[0];
  const int*   ei   = (const int*)d_in[1];
  const float* ea   = (const float*)d_in[2];
  const float* We   = (const float*)d_in[4];
  const float* Whu  = (const float*)d_in[5];
  const float* Whw  = (const float*)d_in[6];
  const float* Wa   = (const float*)d_in[7];
  const float* Wi   = (const float*)d_in[8];
  const float* Wh   = (const float*)d_in[9];
  const float* bih  = (const float*)d_in[10];
  const float* bhh  = (const float*)d_in[11];
  float* out = (float*)d_out;
  float* emb = out;
  float* msg = out + (size_t)N_NODES*128;

  if (ws_size < 94200000) return;
  char* ws = (char*)d_ws;
  unsigned short* msgb   = (unsigned short*)(ws);                 // 81,920,000
  float*          agg    = (float*)(ws + 81920000);               // 10,240,000
  unsigned short* WcatB  = (unsigned short*)(ws + 92160000);      //     98,304
  unsigned short* WaB    = (unsigned short*)(ws + 92258304);      //    131,072
  unsigned short* WiB    = (unsigned short*)(ws + 92389376);      //     98,304
  unsigned short* WhB    = (unsigned short*)(ws + 92487680);      //     98,304
  int*            cnt    = (int*)(ws + 92585984);                 //     80,000
  int*            off    = (int*)(ws + 92665984);                 //     80,016
  int*            cursor = (int*)(ws + 92746000);                 //     80,000
  int*            sorted = (int*)(ws + 92826000);                 //  1,280,000

  hipMemsetAsync(agg, 0, (size_t)N_NODES*128*4, stream);
  hipMemsetAsync(cnt, 0, (size_t)N_NODES*4, stream);
  k_prep<<<832,256,0,stream>>>(We,Whu,Whw,Wa,Wi,Wh,WcatB,WaB,WiB,WhB);
  k_hist<<<1250,256,0,stream>>>(ei, cnt);
  k_scan<<<1,1024,0,stream>>>(cnt, off, cursor);
  k_scatter<<<1250,256,0,stream>>>(ei, cursor, sorted);
  k_messages<<<5000,256,0,stream>>>(ea, ei, x, WcatB, msg, msgb);
  k_attn<<<N_NODES,256,0,stream>>>(msgb, WaB, ei, off, sorted, agg);
  k_gru<<<313,256,0,stream>>>(x, agg, WiB, WhB, bih, bhh, emb);
}